// Round 1
// baseline (496.702 us; speedup 1.0000x reference)
//
#include <hip/hip_runtime.h>
#include <hip/hip_bf16.h>
#include <stdint.h>

typedef __attribute__((ext_vector_type(8))) short bf16x8;
typedef __attribute__((ext_vector_type(4))) float f32x4;

static constexpr int D = 128;
static constexpr int M = 131072;
static constexpr int KHALF = 65536;   // M/2
static constexpr int FIVE_D = 640;
static constexpr int FLAGBIT = 1 << 30;
static constexpr int IDXMASK = FLAGBIT - 1;

__device__ __forceinline__ short f2bf(float x) {
  __hip_bfloat16 h = __float2bfloat16(x);
  return (short)__bfloat16_as_ushort(h);
}

// Invert the scatter: tab[to] = from | (pool<<30). Left uses (bot0, prev0), right (bot1, prev1).
__global__ void build_tables(const int* __restrict__ bf0, const int* __restrict__ bt0,
                             const int* __restrict__ pf0, const int* __restrict__ pt0,
                             const int* __restrict__ bf1, const int* __restrict__ bt1,
                             const int* __restrict__ pf1, const int* __restrict__ pt1,
                             int* __restrict__ tabL, int* __restrict__ tabR) {
  int j = blockIdx.x * blockDim.x + threadIdx.x;
  if (j < KHALF) {
    tabL[bt0[j]] = bf0[j];
    tabL[pt0[j]] = pf0[j] | FLAGBIT;
    tabR[bt1[j]] = bf1[j];
    tabR[pt1[j]] = pf1[j] | FLAGBIT;
  }
}

// Pack + convert W [256,640] f32 row-major -> bf16 Wp[c][n][kk] (c = k-chunk of 32).
// Every MFMA B-fragment (c, n, quad) is a contiguous 16B at Wp + c*20480 + n*32 + quad*8,
// so the fused kernel reads B straight from global (L2-resident, no LDS, no barriers).
__global__ void pack_w(const float* __restrict__ W, unsigned short* __restrict__ P) {
  int idx = blockIdx.x * blockDim.x + threadIdx.x;  // < 8*640*32 = 163840
  int c = idx / (FIVE_D * 32);
  int rem = idx - c * (FIVE_D * 32);
  int n = rem >> 5;
  int kk = rem & 31;
  P[idx] = __bfloat16_as_ushort(__float2bfloat16(W[(c * 32 + kk) * FIVE_D + n]));
}

__global__ __launch_bounds__(512, 4) void tree_lstm_fused(
    const float* __restrict__ h_bot, const float* __restrict__ c_bot,
    const float* __restrict__ h_buf, const float* __restrict__ c_buf,
    const unsigned short* __restrict__ Wp, const float* __restrict__ bias,
    const int* __restrict__ tabL, const int* __restrict__ tabR,
    float* __restrict__ out) {
  // A tile (64 rows x 256 k bf16 = 32KB) staged ONCE, in k-major 16B granules:
  // granule G = kg*64 + row holds row's k in [kg*8, kg*8+8).
  // Both the staging ds_write and the fragment ds_read_b128 put exactly 8 lanes on
  // each bank-quad -> conflict-free with no swizzle.
  __shared__ __align__(16) short A_lds[64 * 256];

  const int tid = threadIdx.x;
  const int lane = tid & 63;
  const int wv = tid >> 6;      // wave id 0..7 = in-gate 16-col chunk
  const int quad = lane >> 4;   // 0..3
  const int l16 = lane & 15;
  const int m_base = blockIdx.x * 64;

  // ---- stage whole A tile: thread t -> row t>>3, 4 consecutive granules, 128B
  // contiguous from ONE source row. All 8 float4 gathers issue back-to-back (ILP),
  // single __syncthreads() for the entire kernel.
  {
    const int row = tid >> 3;
    const int gs0 = (tid & 7) * 4;  // 0,4,...,28 ; gs0<16 -> h_l half, else h_r half
    const int mA = m_base + row;
    const int s = (gs0 < 16) ? tabL[mA] : tabR[mA];
    const float* src = ((s & FLAGBIT) ? h_buf : h_bot) + (size_t)(s & IDXMASK) * D
                     + (gs0 * 8 & 127);  // float offset within the source row
    float4 v[8];
#pragma unroll
    for (int i = 0; i < 8; ++i) v[i] = ((const float4*)src)[i];
#pragma unroll
    for (int j = 0; j < 4; ++j) {
      bf16x8 g;
      g[0] = f2bf(v[2 * j].x);
      g[1] = f2bf(v[2 * j].y);
      g[2] = f2bf(v[2 * j].z);
      g[3] = f2bf(v[2 * j].w);
      g[4] = f2bf(v[2 * j + 1].x);
      g[5] = f2bf(v[2 * j + 1].y);
      g[6] = f2bf(v[2 * j + 1].z);
      g[7] = f2bf(v[2 * j + 1].w);
      *(bf16x8*)&A_lds[((gs0 + j) * 64 + row) * 8] = g;
    }
  }
  __syncthreads();  // the only barrier

  f32x4 acc[4][5];  // 4 M-subtiles x 5 gates -> 80 VGPRs
  const f32x4 zero = {0.f, 0.f, 0.f, 0.f};
#pragma unroll
  for (int mt = 0; mt < 4; ++mt)
#pragma unroll
    for (int g = 0; g < 5; ++g) acc[mt][g] = zero;

  // Per-lane bases; all loop offsets are compile-time immediates after full unroll.
  const short* a_ptr = &A_lds[(quad * 64 + l16) * 8];                 // + c*2048 + mt*128
  const unsigned short* b_ptr = Wp + (wv * 512 + l16 * 32 + quad * 8);  // + c*20480 + g*4096

  // ---- barrier-free K loop: ds_read + L2-resident global B load + MFMA.
#pragma unroll
  for (int c = 0; c < 8; ++c) {
    bf16x8 af[4];
#pragma unroll
    for (int mt = 0; mt < 4; ++mt)
      af[mt] = *(const bf16x8*)(a_ptr + c * 2048 + mt * 128);
#pragma unroll
    for (int g = 0; g < 5; ++g) {
      const bf16x8 bf_ = *(const bf16x8*)(b_ptr + c * 20480 + g * 4096);
#pragma unroll
      for (int mt = 0; mt < 4; ++mt)
        acc[mt][g] = __builtin_amdgcn_mfma_f32_16x16x32_bf16(af[mt], bf_, acc[mt][g], 0, 0, 0);
    }
  }

  // Epilogue: wave wv holds gates i,o,u,fl,fr for rows m_base+mt*16+quad*4+r at
  // in-gate col d = wv*16 + l16. C/D layout: col=lane&15, row=quad*4+reg (m89/m91).
  // c_l/c_r gathers hoisted per-mt so 8 loads are in flight before the VALU chain.
  const int d = wv * 16 + l16;
  const float bi = bias[0 * D + d];
  const float bo = bias[1 * D + d];
  const float bu = bias[2 * D + d];
  const float bl = bias[3 * D + d];
  const float br = bias[4 * D + d];
  float* outh = out;
  float* outc = out + (size_t)M * D;

#pragma unroll
  for (int mt = 0; mt < 4; ++mt) {
    float cl[4], cr[4];
#pragma unroll
    for (int r = 0; r < 4; ++r) {
      const int m = m_base + mt * 16 + quad * 4 + r;
      const int sL = tabL[m];
      const int sR = tabR[m];
      cl[r] = (((sL & FLAGBIT) ? c_buf : c_bot) + (size_t)(sL & IDXMASK) * D)[d];
      cr[r] = (((sR & FLAGBIT) ? c_buf : c_bot) + (size_t)(sR & IDXMASK) * D)[d];
    }
#pragma unroll
    for (int r = 0; r < 4; ++r) {
      const int m = m_base + mt * 16 + quad * 4 + r;
      const float gi = acc[mt][0][r] + bi;
      const float go = acc[mt][1][r] + bo;
      const float gu = acc[mt][2][r] + bu;
      const float gfl = acc[mt][3][r] + bl;
      const float gfr = acc[mt][4][r] + br;
      const float iv = 1.f / (1.f + __expf(-gi));
      const float ov = 1.f / (1.f + __expf(-go));
      const float uv = 2.f / (1.f + __expf(-2.f * gu)) - 1.f;  // tanh, inf-safe
      const float flv = 1.f / (1.f + __expf(-gfl));
      const float frv = 1.f / (1.f + __expf(-gfr));
      const float cc = iv * uv + flv * cl[r] + frv * cr[r];
      const float hh = ov * (2.f / (1.f + __expf(-2.f * cc)) - 1.f);
      // streamed once-written output: nontemporal, keep L2/LLC for gather rows + W
      __builtin_nontemporal_store(hh, &outh[(size_t)m * D + d]);
      __builtin_nontemporal_store(cc, &outc[(size_t)m * D + d]);
    }
  }
}

extern "C" void kernel_launch(void* const* d_in, const int* in_sizes, int n_in,
                              void* d_out, int out_size, void* d_ws, size_t ws_size,
                              hipStream_t stream) {
  const float* h_bot = (const float*)d_in[0];
  const float* c_bot = (const float*)d_in[1];
  const float* h_buf = (const float*)d_in[2];
  const float* c_buf = (const float*)d_in[3];
  const float* W = (const float*)d_in[4];
  const float* b = (const float*)d_in[5];
  const int* bf0 = (const int*)d_in[6];
  const int* bt0 = (const int*)d_in[7];
  const int* pf0 = (const int*)d_in[8];
  const int* pt0 = (const int*)d_in[9];
  const int* bf1 = (const int*)d_in[10];
  const int* bt1 = (const int*)d_in[11];
  const int* pf1 = (const int*)d_in[12];
  const int* pt1 = (const int*)d_in[13];

  int* tabL = (int*)d_ws;                            // M int32
  int* tabR = tabL + M;                              // M int32
  unsigned short* Wp = (unsigned short*)(tabR + M);  // 163840 bf16

  hipLaunchKernelGGL(build_tables, dim3(KHALF / 256), dim3(256), 0, stream,
                     bf0, bt0, pf0, pt0, bf1, bt1, pf1, pt1, tabL, tabR);
  hipLaunchKernelGGL(pack_w, dim3((8 * FIVE_D * 32) / 256), dim3(256), 0, stream, W, Wp);
  hipLaunchKernelGGL(tree_lstm_fused, dim3(M / 64), dim3(512), 0, stream,
                     h_bot, c_bot, h_buf, c_buf, Wp, b, tabL, tabR, (float*)d_out);
}